// Round 4
// baseline (148.436 us; speedup 1.0000x reference)
//
#include <hip/hip_runtime.h>
#include <math.h>

#define N_FRAMES 20000
#define N_BEADS  50
#define N_DIST   1225   // sum_{inc=1}^{49} (50-inc)
#define N_ANG    48
#define N_DIH    47
#define OUT_STRIDE (N_DIST + N_ANG + 2 * N_DIH)  // 1367
#define FPB      8              // frames per block; 20000/8 = 2500 blocks
#define FRAME_F  (N_BEADS * 3)  // 150 packed floats per frame (global)
#define FRAME_P  (N_BEADS * 4)  // 200 padded floats per frame (LDS, float4/bead)

// cumulative pair count before separation `inc`:
// cum(inc) = sum_{k=1}^{inc-1} (50-k) = (inc-1)*50 - (inc-1)*inc/2
__device__ __forceinline__ int cum_pairs(int inc) {
    return (inc - 1) * 50 - ((inc - 1) * inc) / 2;
}

__global__ __launch_bounds__(256)
void protein_feat_kernel(const float* __restrict__ data, float* __restrict__ out) {
    const int tid = threadIdx.x;
    const int f0  = blockIdx.x * FPB;

    // padded layout: one float4 per bead -> single ds_read_b128 per bead
    __shared__ __align__(16) float s[FPB * FRAME_P];  // 8 * 200 * 4B = 6.4 KB

    // ---- stage 8 frames: float4 global loads, repack packed->padded ----
    // identity: global float index gi (across whole block's 1200 floats)
    // maps to padded LDS index (gi/3)*4 + gi%3  (works across frame bounds
    // because FRAME_P = (FRAME_F/3)*4)
    {
        const float4* g4 = (const float4*)(data + (size_t)f0 * FRAME_F);
        for (int x = tid; x < FPB * FRAME_F / 4; x += 256) {
            float4 v = g4[x];
            int gi = 4 * x;
#pragma unroll
            for (int c = 0; c < 4; ++c) {
                int B  = (gi + c) / 3;
                int cc = (gi + c) - 3 * B;
                s[B * 4 + cc] = (&v.x)[c];
            }
        }
    }
    __syncthreads();

    // ---- precompute this thread's pair bead-indices ONCE (frame-independent) ----
    int bi_idx[5], bj_idx[5];
#pragma unroll
    for (int k = 0; k < 5; ++k) {
        int p = tid + k * 256;
        if (p < N_DIST) {
            float disc = 9801.0f - 8.0f * (float)p;
            int inc = (int)((101.0f - sqrtf(disc)) * 0.5f);
            inc = min(max(inc, 1), 49);
            while (inc < 49 && cum_pairs(inc + 1) <= p) ++inc;  // float-rounding fixup
            while (inc > 1  && cum_pairs(inc)     >  p) --inc;
            int i = p - cum_pairs(inc);
            bi_idx[k] = i;
            bj_idx[k] = i + inc;
        } else {
            bi_idx[k] = 0; bj_idx[k] = 0;
        }
    }

    // ---- distances: frame loop NOT unrolled (keep VGPR pressure low) ----
#pragma unroll 1
    for (int f = 0; f < FPB; ++f) {
        const float4* sf4 = (const float4*)s + f * N_BEADS;
        float* fout = out + (size_t)(f0 + f) * OUT_STRIDE;
#pragma unroll
        for (int k = 0; k < 5; ++k) {
            int p = tid + k * 256;
            if (p < N_DIST) {
                float4 bi = sf4[bi_idx[k]];
                float4 bj = sf4[bj_idx[k]];
                float dx = bj.x - bi.x;
                float dy = bj.y - bi.y;
                float dz = bj.z - bi.z;
                __builtin_nontemporal_store(sqrtf(dx * dx + dy * dy + dz * dz),
                                            &fout[p]);
            }
        }
    }

    // ---- angles: 8 frames x 48 = 384 items ----
#pragma unroll 1
    for (int idx = tid; idx < FPB * N_ANG; idx += 256) {
        int f = idx / N_ANG;
        int a = idx - f * N_ANG;
        const float4* sf4 = (const float4*)s + f * N_BEADS;
        float4 A = sf4[a], B = sf4[a + 1], C = sf4[a + 2];
        float b1x = A.x - B.x, b1y = A.y - B.y, b1z = A.z - B.z;
        float b2x = C.x - B.x, b2y = C.y - B.y, b2z = C.z - B.z;
        float dot = b1x * b2x + b1y * b2y + b1z * b2z;
        float n1 = sqrtf(b1x * b1x + b1y * b1y + b1z * b1z);
        float n2 = sqrtf(b2x * b2x + b2y * b2y + b2z * b2z);
        float c = dot / (n1 * n2);
        c = fminf(1.0f, fmaxf(-1.0f, c));
        __builtin_nontemporal_store(acosf(c),
            &out[(size_t)(f0 + f) * OUT_STRIDE + N_DIST + a]);
    }

    // ---- dihedrals: 8 frames x 47 = 376 items ----
#pragma unroll 1
    for (int idx = tid; idx < FPB * N_DIH; idx += 256) {
        int f = idx / N_DIH;
        int d = idx - f * N_DIH;
        const float4* sf4 = (const float4*)s + f * N_BEADS;
        float4 P0 = sf4[d], P1 = sf4[d + 1], P2 = sf4[d + 2], P3 = sf4[d + 3];

        float ax = P1.x - P0.x, ay = P1.y - P0.y, az = P1.z - P0.z;
        float bx = P2.x - P1.x, by = P2.y - P1.y, bz = P2.z - P1.z;
        float cx = P3.x - P2.x, cy = P3.y - P2.y, cz = P3.z - P2.z;

        // p1 = a x b ; p2 = b x c
        float p1x = ay * bz - az * by;
        float p1y = az * bx - ax * bz;
        float p1z = ax * by - ay * bx;
        float p2x = by * cz - bz * cy;
        float p2y = bz * cx - bx * cz;
        float p2z = bx * cy - by * cx;

        float n1 = sqrtf(p1x * p1x + p1y * p1y + p1z * p1z);
        float n2 = sqrtf(p2x * p2x + p2y * p2y + p2z * p2z);
        float nb = sqrtf(bx * bx + by * by + bz * bz);

        float dotp = p1x * p2x + p1y * p2y + p1z * p2z;
        // (p1 x p2) . b
        float qx = p1y * p2z - p1z * p2y;
        float qy = p1z * p2x - p1x * p2z;
        float qz = p1x * p2y - p1y * p2x;
        float trip = qx * bx + qy * by + qz * bz;

        float inv12 = 1.0f / (n1 * n2);
        size_t base = (size_t)(f0 + f) * OUT_STRIDE + N_DIST + N_ANG;
        __builtin_nontemporal_store(dotp * inv12, &out[base + d]);
        __builtin_nontemporal_store(trip * inv12 / nb, &out[base + N_DIH + d]);
    }
}

extern "C" void kernel_launch(void* const* d_in, const int* in_sizes, int n_in,
                              void* d_out, int out_size, void* d_ws, size_t ws_size,
                              hipStream_t stream) {
    const float* data = (const float*)d_in[0];
    float* out = (float*)d_out;
    protein_feat_kernel<<<N_FRAMES / FPB, 256, 0, stream>>>(data, out);
}

// Round 5
// 131.057 us; speedup vs baseline: 1.1326x; 1.1326x over previous
//
#include <hip/hip_runtime.h>
#include <math.h>

#define N_FRAMES 20000
#define N_BEADS  50
#define N_DIST   1225   // sum_{inc=1}^{49} (50-inc)
#define N_ANG    48
#define N_DIH    47
#define OUT_STRIDE (N_DIST + N_ANG + 2 * N_DIH)  // 1367
#define FPB      8              // frames per block; 20000/8 = 2500 blocks
#define FRAME_F  (N_BEADS * 3)  // 150 packed floats per frame (global)
#define FRAME_P  (N_BEADS * 4)  // 200 padded floats per frame (LDS, float4/bead)

// cumulative pair count before separation `inc`:
// cum(inc) = sum_{k=1}^{inc-1} (50-k) = (inc-1)*50 - (inc-1)*inc/2
__device__ __forceinline__ int cum_pairs(int inc) {
    return (inc - 1) * 50 - ((inc - 1) * inc) / 2;
}

// launch_bounds(256,3): guardrail so the allocator keeps VGPR <= ~168
// (>=3 waves/EU -> >=3 blocks/CU of 256 threads). Full unroll in R2/R3
// plausibly blew past 256 VGPR -> 1 block/CU -> no latency hiding.
__global__ __launch_bounds__(256, 3)
void protein_feat_kernel(const float* __restrict__ data, float* __restrict__ out) {
    const int tid = threadIdx.x;
    const int f0  = blockIdx.x * FPB;

    // padded layout: one float4 per bead -> single ds_read_b128 per bead
    __shared__ __align__(16) float s[FPB * FRAME_P];  // 8 * 200 * 4B = 6.4 KB

    // ---- stage 8 frames: float4 global loads, repack packed->padded ----
    {
        const float4* g4 = (const float4*)(data + (size_t)f0 * FRAME_F);
        for (int x = tid; x < FPB * FRAME_F / 4; x += 256) {
            float4 v = g4[x];
            int gi = 4 * x;
#pragma unroll
            for (int c = 0; c < 4; ++c) {
                int B  = (gi + c) / 3;
                int cc = (gi + c) - 3 * B;
                s[B * 4 + cc] = (&v.x)[c];
            }
        }
    }
    __syncthreads();

    // ---- precompute this thread's pair bead-indices ONCE (frame-independent) ----
    int bi_idx[5], bj_idx[5];
#pragma unroll
    for (int k = 0; k < 5; ++k) {
        int p = tid + k * 256;
        if (p < N_DIST) {
            float disc = 9801.0f - 8.0f * (float)p;
            int inc = (int)((101.0f - sqrtf(disc)) * 0.5f);
            inc = min(max(inc, 1), 49);
            while (inc < 49 && cum_pairs(inc + 1) <= p) ++inc;  // float-rounding fixup
            while (inc > 1  && cum_pairs(inc)     >  p) --inc;
            int i = p - cum_pairs(inc);
            bi_idx[k] = i;
            bj_idx[k] = i + inc;
        } else {
            bi_idx[k] = 0; bj_idx[k] = 0;
        }
    }
    const bool has_tail = (1024 + tid) < N_DIST;  // tid < 201

    // ---- distances: moderate unroll (2 frames = 10 pairs in flight) ----
#pragma unroll 2
    for (int f = 0; f < FPB; ++f) {
        const float4* sf4 = (const float4*)s + f * N_BEADS;
        float* fout = out + (size_t)(f0 + f) * OUT_STRIDE;
#pragma unroll
        for (int k = 0; k < 4; ++k) {   // p = tid + k*256 < 1024 < N_DIST always
            float4 bi = sf4[bi_idx[k]];
            float4 bj = sf4[bj_idx[k]];
            float dx = bj.x - bi.x;
            float dy = bj.y - bi.y;
            float dz = bj.z - bi.z;
            fout[tid + k * 256] = sqrtf(dx * dx + dy * dy + dz * dz);
        }
        if (has_tail) {
            float4 bi = sf4[bi_idx[4]];
            float4 bj = sf4[bj_idx[4]];
            float dx = bj.x - bi.x;
            float dy = bj.y - bi.y;
            float dz = bj.z - bi.z;
            fout[tid + 1024] = sqrtf(dx * dx + dy * dy + dz * dz);
        }
    }

    // ---- angles: 8 frames x 48 = 384 items ----
#pragma unroll 1
    for (int idx = tid; idx < FPB * N_ANG; idx += 256) {
        int f = idx / N_ANG;
        int a = idx - f * N_ANG;
        const float4* sf4 = (const float4*)s + f * N_BEADS;
        float4 A = sf4[a], B = sf4[a + 1], C = sf4[a + 2];
        float b1x = A.x - B.x, b1y = A.y - B.y, b1z = A.z - B.z;
        float b2x = C.x - B.x, b2y = C.y - B.y, b2z = C.z - B.z;
        float dot = b1x * b2x + b1y * b2y + b1z * b2z;
        float n1 = sqrtf(b1x * b1x + b1y * b1y + b1z * b1z);
        float n2 = sqrtf(b2x * b2x + b2y * b2y + b2z * b2z);
        float c = dot / (n1 * n2);
        c = fminf(1.0f, fmaxf(-1.0f, c));
        out[(size_t)(f0 + f) * OUT_STRIDE + N_DIST + a] = acosf(c);
    }

    // ---- dihedrals: 8 frames x 47 = 376 items ----
#pragma unroll 1
    for (int idx = tid; idx < FPB * N_DIH; idx += 256) {
        int f = idx / N_DIH;
        int d = idx - f * N_DIH;
        const float4* sf4 = (const float4*)s + f * N_BEADS;
        float4 P0 = sf4[d], P1 = sf4[d + 1], P2 = sf4[d + 2], P3 = sf4[d + 3];

        float ax = P1.x - P0.x, ay = P1.y - P0.y, az = P1.z - P0.z;
        float bx = P2.x - P1.x, by = P2.y - P1.y, bz = P2.z - P1.z;
        float cx = P3.x - P2.x, cy = P3.y - P2.y, cz = P3.z - P2.z;

        // p1 = a x b ; p2 = b x c
        float p1x = ay * bz - az * by;
        float p1y = az * bx - ax * bz;
        float p1z = ax * by - ay * bx;
        float p2x = by * cz - bz * cy;
        float p2y = bz * cx - bx * cz;
        float p2z = bx * cy - by * cx;

        float n1 = sqrtf(p1x * p1x + p1y * p1y + p1z * p1z);
        float n2 = sqrtf(p2x * p2x + p2y * p2y + p2z * p2z);
        float nb = sqrtf(bx * bx + by * by + bz * bz);

        float dotp = p1x * p2x + p1y * p2y + p1z * p2z;
        // (p1 x p2) . b
        float qx = p1y * p2z - p1z * p2y;
        float qy = p1z * p2x - p1x * p2z;
        float qz = p1x * p2y - p1y * p2x;
        float trip = qx * bx + qy * by + qz * bz;

        float inv12 = 1.0f / (n1 * n2);
        size_t base = (size_t)(f0 + f) * OUT_STRIDE + N_DIST + N_ANG;
        out[base + d]         = dotp * inv12;
        out[base + N_DIH + d] = trip * inv12 / nb;
    }
}

extern "C" void kernel_launch(void* const* d_in, const int* in_sizes, int n_in,
                              void* d_out, int out_size, void* d_ws, size_t ws_size,
                              hipStream_t stream) {
    const float* data = (const float*)d_in[0];
    float* out = (float*)d_out;
    protein_feat_kernel<<<N_FRAMES / FPB, 256, 0, stream>>>(data, out);
}